// Round 13
// baseline (157.891 us; speedup 1.0000x reference)
//
#include <hip/hip_runtime.h>

#define BSHIFT 9
#define BW 512            // nodes per bucket == bins
#define BLK 512
#define BLKL 256          // block size for layer kernels
#define CHUNK 8192        // edges per k_bin block (16/thread)
#define CSR_CAP 18432     // LDS staging capacity (expected bucket ~16.4K edges)

// ---- block-wide exclusive scan over BLK=512 ints (wave shfl + 8-entry LDS) ----
__device__ __forceinline__ int blockScanExcl512(int v, int tid, int* wsum) {
    int lane = tid & 63;
    int w = tid >> 6;                       // 8 waves
    int incl = v;
#pragma unroll
    for (int d = 1; d < 64; d <<= 1) {
        int u = __shfl_up(incl, d, 64);
        if (lane >= d) incl += u;
    }
    if (lane == 63) wsum[w] = incl;
    __syncthreads();
    if (tid < 64) {
        int x = (tid < 8) ? wsum[tid] : 0;
#pragma unroll
        for (int d = 1; d < 8; d <<= 1) {
            int u = __shfl_up(x, d, 64);
            if (lane >= d) x += u;
        }
        if (tid < 8) wsum[tid] = x;         // inclusive scan of wave totals
    }
    __syncthreads();
    int base = (w == 0) ? 0 : wsum[w - 1];
    return base + incl - v;
}

// ---------------- pass 1: bucket histogram (int4 loads, 4 LDS replicas) ----------------
__global__ __launch_bounds__(BLK) void k_bhist(const int* __restrict__ dst,
                                               int* __restrict__ bucketCount, int E) {
    __shared__ int h[4][BW];
    int t = threadIdx.x;
#pragma unroll
    for (int r = 0; r < 4; ++r) h[r][t] = 0;
    __syncthreads();
    int* hr = h[(t >> 6) & 3];
    int gtid = blockIdx.x * BLK + t;
    int stride = gridDim.x * BLK;
    const int4* dst4 = (const int4*)dst;
    int E4 = E >> 2;
    for (int i = gtid; i < E4; i += stride) {
        int4 d = dst4[i];
        atomicAdd(&hr[d.x >> BSHIFT], 1);
        atomicAdd(&hr[d.y >> BSHIFT], 1);
        atomicAdd(&hr[d.z >> BSHIFT], 1);
        atomicAdd(&hr[d.w >> BSHIFT], 1);
    }
    for (int i = (E4 << 2) + gtid; i < E; i += stride)
        atomicAdd(&hr[dst[i] >> BSHIFT], 1);
    __syncthreads();
    int s = h[0][t] + h[1][t] + h[2][t] + h[3][t];
    if (s) atomicAdd(&bucketCount[t], s);
}

// ---------------- pass 2: bucket scan (1 block) ----------------
__global__ __launch_bounds__(BLK) void k_bscan(const int* __restrict__ bucketCount,
                                               int* __restrict__ bucketBase,
                                               int* __restrict__ bucketCursor,
                                               int NB, int E) {
    __shared__ int wsum[8];
    int t = threadIdx.x;
    int v = (t < NB) ? bucketCount[t] : 0;
    int ex = blockScanExcl512(v, t, wsum);
    if (t < NB) { bucketBase[t] = ex; bucketCursor[t] = ex; }
    if (t == NB) bucketBase[t] = E;
}

// ---------------- pass 3: chunk counting-sort by dst-bucket, coalesced flush ----------------
__global__ __launch_bounds__(BLK) void k_bin(const int* __restrict__ src,
                                             const int* __restrict__ dst,
                                             int* __restrict__ bucketCursor,
                                             unsigned int* __restrict__ binned, int E) {
    __shared__ int h0[BW], h1[BW];
    __shared__ int excl[BW], cur[BW], gbase[BW];
    __shared__ unsigned int vals[CHUNK];      // 32 KB
    __shared__ unsigned short bkt[CHUNK];     // 16 KB
    __shared__ int wsum[8];
    int t = threadIdx.x;
    int base = blockIdx.x * CHUNK;
    int cnt = min(CHUNK, E - base);
    h0[t] = 0; h1[t] = 0;
    __syncthreads();
    int* hr = ((t >> 6) & 1) ? h1 : h0;

    int d16[16], s16[16];
    int myBase = base + t * 16;
    int nb = 0;
    if (myBase + 16 <= E) {
        const int4* dp = (const int4*)(dst + myBase);
        const int4* sp = (const int4*)(src + myBase);
#pragma unroll
        for (int k = 0; k < 4; ++k) {
            int4 a = dp[k];
            d16[4 * k] = a.x; d16[4 * k + 1] = a.y; d16[4 * k + 2] = a.z; d16[4 * k + 3] = a.w;
            int4 c = sp[k];
            s16[4 * k] = c.x; s16[4 * k + 1] = c.y; s16[4 * k + 2] = c.z; s16[4 * k + 3] = c.w;
        }
        nb = 16;
    } else {
        for (int k = 0; k < 16; ++k) {
            int idx = myBase + k;
            if (idx < E) { d16[k] = dst[idx]; s16[k] = src[idx]; ++nb; }
        }
    }
    for (int k = 0; k < nb; ++k) atomicAdd(&hr[d16[k] >> BSHIFT], 1);
    __syncthreads();
    int hv = h0[t] + h1[t];
    int ex = blockScanExcl512(hv, t, wsum);
    excl[t] = ex;
    cur[t] = ex;
    if (hv) gbase[t] = atomicAdd(&bucketCursor[t], hv);
    __syncthreads();
    for (int k = 0; k < nb; ++k) {
        int b = d16[k] >> BSHIFT;
        int r = atomicAdd(&cur[b], 1);
        vals[r] = ((unsigned int)s16[k] << BSHIFT) | (unsigned int)(d16[k] & (BW - 1));
        bkt[r] = (unsigned short)b;
    }
    __syncthreads();
    for (int i = t; i < cnt; i += BLK) {
        int b = bkt[i];
        binned[gbase[b] + (i - excl[b])] = vals[i];
    }
}

// ---------------- pass 4: per-bucket per-node counting sort -> CSR (+deg/dinv/xd) ----------------
__global__ __launch_bounds__(BLK) void k_csr(const unsigned int* __restrict__ binned,
                                             const int* __restrict__ bucketBase,
                                             const float* __restrict__ x,
                                             int* __restrict__ csrOff,
                                             int* __restrict__ deg,
                                             float* __restrict__ dinv,
                                             float* __restrict__ xd,
                                             int* __restrict__ csrSrc, int n) {
    __shared__ int dh0[BW], dh1[BW];
    __shared__ int cursor[BW];
    __shared__ int wsum[8];
    __shared__ int stage[CSR_CAP];         // 72 KB
    int t = threadIdx.x;
    int b = blockIdx.x;
    int ebase = bucketBase[b];
    int ecnt = bucketBase[b + 1] - ebase;
    dh0[t] = 0; dh1[t] = 0;
    __syncthreads();
    int* dh = ((t >> 6) & 1) ? dh1 : dh0;
    for (int i = t; i < ecnt; i += BLK)
        atomicAdd(&dh[binned[ebase + i] & (BW - 1)], 1);
    __syncthreads();
    int c = dh0[t] + dh1[t];
    int ex = blockScanExcl512(c, t, wsum);
    cursor[t] = ex;
    int nodeBase = b << BSHIFT;
    if (t < min(BW, n - nodeBase)) {
        int node = nodeBase + t;
        csrOff[node] = ebase + ex;
        deg[node] = c;
        float r = rsqrtf((float)(c + 1));
        dinv[node] = r;
        xd[node] = x[node] * r;
    }
    __syncthreads();
    for (int i = t; i < ecnt; i += BLK) {
        unsigned int v = binned[ebase + i];
        int r = atomicAdd(&cursor[v & (BW - 1)], 1);
        int sv = (int)(v >> BSHIFT);
        if (r < CSR_CAP) stage[r] = sv;
        else csrSrc[ebase + r] = sv;
    }
    __syncthreads();
    int m = min(ecnt, CSR_CAP);
    for (int i = t; i < m; i += BLK)
        csrSrc[ebase + i] = stage[i];
}

// ---------------- pass 5: layer-1 scalar aggregate -> spk[n] = pack(s_i, deg8) ----------------
__global__ __launch_bounds__(BLKL) void k_l1(const int* __restrict__ csrOff,
                                             const int* __restrict__ deg,
                                             const int* __restrict__ csrSrc,
                                             const float* __restrict__ xd,
                                             const float* __restrict__ dinv,
                                             unsigned int* __restrict__ spk, int n) {
    int tid = threadIdx.x;
    int q = tid & 3;
    int node = blockIdx.x * (BLKL / 4) + (tid >> 2);
    if (node >= n) return;
    int start = csrOff[node];
    int dc = deg[node];
    float u = 0.f;
    int e = q;
    for (; e + 4 < dc; e += 8) {
        int s0 = csrSrc[start + e];
        int s1 = csrSrc[start + e + 4];
        u += xd[s0] + xd[s1];
    }
    for (; e < dc; e += 4)
        u += xd[csrSrc[start + e]];
    u += __shfl_xor(u, 1, 64);
    u += __shfl_xor(u, 2, 64);
    if (q == 0) {
        float di = dinv[node];
        float s = di * (u + xd[node]);
        unsigned int us = (__float_as_uint(s) + 0x80u) & 0xFFFFFF00u;  // round to 24-bit
        unsigned int d8 = (unsigned int)min(dc, 255);
        spk[node] = us | d8;
    }
}

// ---------------- pass 6: layer-2, 2 nodes per quad (cross-node ILP), packed 4B gather ----------------
// G_j = sum_src relu(W1[j]*s_src+b1[j])*di_src (+self);  A[k]=sum_j W2[j][k]*G_j
// out[i] = relu(dinv_i*A + b2) . Wl + bl
__global__ __launch_bounds__(BLKL) void k_l2(const int* __restrict__ csrOff,
                                             const int* __restrict__ deg,
                                             const int* __restrict__ csrSrc,
                                             const unsigned int* __restrict__ spk,
                                             const float* __restrict__ dinv,
                                             const float* __restrict__ W1,
                                             const float* __restrict__ b1,
                                             const float* __restrict__ W2,
                                             const float* __restrict__ b2,
                                             const float* __restrict__ Wl,
                                             const float* __restrict__ bl,
                                             float* __restrict__ out, int n) {
    __shared__ float sW2[256];
    __shared__ float di_tab[256];
    int tid = threadIdx.x;
    sW2[tid] = W2[tid];
    di_tab[tid] = rsqrtf((float)(tid + 1));   // exact di for deg 0..254
    int q = tid & 3;
    int nodeA = blockIdx.x * (BLKL / 2) + (tid >> 2) * 2;
    int nodeB = nodeA + 1;

    float w1r[16], b1r[16];
#pragma unroll
    for (int j = 0; j < 16; ++j) {
        w1r[j] = W1[j];
        float bv = b1[j];
        asm volatile("" : "+v"(bv));
        b1r[j] = bv;
    }
    float4 b2q = *(const float4*)(b2 + 4 * q);
    float4 wlq = *(const float4*)(Wl + 4 * q);
    float blv = bl[0];
    __syncthreads();
    if (nodeA >= n) return;
    bool hasB = (nodeB < n);

    int sA = csrOff[nodeA], dA = deg[nodeA];
    int sB = hasB ? csrOff[nodeB] : 0;
    int dB = hasB ? deg[nodeB] : 0;

    float GA[16], GB[16];
#pragma unroll
    for (int j = 0; j < 16; ++j) { GA[j] = 0.f; GB[j] = 0.f; }

    unsigned int uselfA = spk[nodeA];
    float dselfA = dinv[nodeA];
    unsigned int uselfB = hasB ? spk[nodeB] : 0u;
    float dselfB = hasB ? dinv[nodeB] : 0.f;
    if (q == 0) {
        float ssA = __uint_as_float(uselfA & 0xFFFFFF00u);
#pragma unroll
        for (int j = 0; j < 16; ++j)
            GA[j] = fmaf(fmaxf(fmaf(w1r[j], ssA, b1r[j]), 0.f), dselfA, GA[j]);
        if (hasB) {
            float ssB = __uint_as_float(uselfB & 0xFFFFFF00u);
#pragma unroll
            for (int j = 0; j < 16; ++j)
                GB[j] = fmaf(fmaxf(fmaf(w1r[j], ssB, b1r[j]), 0.f), dselfB, GB[j]);
        }
    }

#define EDGEACC(Gacc, u, srcidx)                                             \
    {                                                                        \
        float s_ = __uint_as_float((u) & 0xFFFFFF00u);                       \
        unsigned int d8_ = (u) & 255u;                                       \
        float di_ = di_tab[d8_];                                             \
        if (__builtin_expect(d8_ == 255u, 0)) di_ = dinv[srcidx];            \
        _Pragma("unroll")                                                    \
        for (int j = 0; j < 16; ++j)                                         \
            Gacc[j] = fmaf(fmaxf(fmaf(w1r[j], s_, b1r[j]), 0.f), di_, Gacc[j]); \
    }

    int eA = q, eB = q;
    // joint loop: 8 independent gather streams per quad
    while (eA + 12 < dA && eB + 12 < dB) {
        int a0 = csrSrc[sA + eA];
        int a1 = csrSrc[sA + eA + 4];
        int a2 = csrSrc[sA + eA + 8];
        int a3 = csrSrc[sA + eA + 12];
        int b0 = csrSrc[sB + eB];
        int b1i = csrSrc[sB + eB + 4];
        int b2i = csrSrc[sB + eB + 8];
        int b3 = csrSrc[sB + eB + 12];
        unsigned int uA0 = spk[a0], uA1 = spk[a1], uA2 = spk[a2], uA3 = spk[a3];
        unsigned int uB0 = spk[b0], uB1 = spk[b1i], uB2 = spk[b2i], uB3 = spk[b3];
        EDGEACC(GA, uA0, a0) EDGEACC(GA, uA1, a1) EDGEACC(GA, uA2, a2) EDGEACC(GA, uA3, a3)
        EDGEACC(GB, uB0, b0) EDGEACC(GB, uB1, b1i) EDGEACC(GB, uB2, b2i) EDGEACC(GB, uB3, b3)
        eA += 16; eB += 16;
    }
    for (; eA + 12 < dA; eA += 16) {
        int a0 = csrSrc[sA + eA];
        int a1 = csrSrc[sA + eA + 4];
        int a2 = csrSrc[sA + eA + 8];
        int a3 = csrSrc[sA + eA + 12];
        unsigned int u0 = spk[a0], u1 = spk[a1], u2 = spk[a2], u3 = spk[a3];
        EDGEACC(GA, u0, a0) EDGEACC(GA, u1, a1) EDGEACC(GA, u2, a2) EDGEACC(GA, u3, a3)
    }
    for (; eB + 12 < dB; eB += 16) {
        int b0 = csrSrc[sB + eB];
        int b1i = csrSrc[sB + eB + 4];
        int b2i = csrSrc[sB + eB + 8];
        int b3 = csrSrc[sB + eB + 12];
        unsigned int u0 = spk[b0], u1 = spk[b1i], u2 = spk[b2i], u3 = spk[b3];
        EDGEACC(GB, u0, b0) EDGEACC(GB, u1, b1i) EDGEACC(GB, u2, b2i) EDGEACC(GB, u3, b3)
    }
    for (; eA < dA; eA += 4) {
        int a0 = csrSrc[sA + eA];
        unsigned int u0 = spk[a0];
        EDGEACC(GA, u0, a0)
    }
    for (; eB < dB; eB += 4) {
        int b0 = csrSrc[sB + eB];
        unsigned int u0 = spk[b0];
        EDGEACC(GB, u0, b0)
    }
#undef EDGEACC

#pragma unroll
    for (int j = 0; j < 16; ++j) {
        GA[j] += __shfl_xor(GA[j], 1, 64);
        GA[j] += __shfl_xor(GA[j], 2, 64);
        GB[j] += __shfl_xor(GB[j], 1, 64);
        GB[j] += __shfl_xor(GB[j], 2, 64);
    }

    float4 AA = make_float4(0.f, 0.f, 0.f, 0.f);
    float4 AB = make_float4(0.f, 0.f, 0.f, 0.f);
#pragma unroll
    for (int j = 0; j < 16; ++j) {
        float4 w = *(const float4*)(&sW2[j * 16 + 4 * q]);
        AA.x = fmaf(w.x, GA[j], AA.x);
        AA.y = fmaf(w.y, GA[j], AA.y);
        AA.z = fmaf(w.z, GA[j], AA.z);
        AA.w = fmaf(w.w, GA[j], AA.w);
        AB.x = fmaf(w.x, GB[j], AB.x);
        AB.y = fmaf(w.y, GB[j], AB.y);
        AB.z = fmaf(w.z, GB[j], AB.z);
        AB.w = fmaf(w.w, GB[j], AB.w);
    }

    float v0 = fmaxf(fmaf(dselfA, AA.x, b2q.x), 0.f);
    float v1 = fmaxf(fmaf(dselfA, AA.y, b2q.y), 0.f);
    float v2 = fmaxf(fmaf(dselfA, AA.z, b2q.z), 0.f);
    float v3 = fmaxf(fmaf(dselfA, AA.w, b2q.w), 0.f);
    float pA = fmaf(v0, wlq.x, fmaf(v1, wlq.y, fmaf(v2, wlq.z, v3 * wlq.w)));
    pA += __shfl_xor(pA, 1, 64);
    pA += __shfl_xor(pA, 2, 64);
    float w0 = fmaxf(fmaf(dselfB, AB.x, b2q.x), 0.f);
    float w1v = fmaxf(fmaf(dselfB, AB.y, b2q.y), 0.f);
    float w2v = fmaxf(fmaf(dselfB, AB.z, b2q.z), 0.f);
    float w3 = fmaxf(fmaf(dselfB, AB.w, b2q.w), 0.f);
    float pB = fmaf(w0, wlq.x, fmaf(w1v, wlq.y, fmaf(w2v, wlq.z, w3 * wlq.w)));
    pB += __shfl_xor(pB, 1, 64);
    pB += __shfl_xor(pB, 2, 64);
    if (q == 0) {
        out[nodeA] = pA + blv;
        if (hasB) out[nodeB] = pB + blv;
    }
}

extern "C" void kernel_launch(void* const* d_in, const int* in_sizes, int n_in,
                              void* d_out, int out_size, void* d_ws, size_t ws_size,
                              hipStream_t stream) {
    const float* x  = (const float*)d_in[0];
    const int*   ei = (const int*)d_in[1];
    const float* W1 = (const float*)d_in[2];
    const float* b1 = (const float*)d_in[3];
    const float* W2 = (const float*)d_in[4];
    const float* b2 = (const float*)d_in[5];
    const float* Wl = (const float*)d_in[6];
    const float* bl = (const float*)d_in[7];
    float* out = (float*)d_out;

    int n = in_sizes[0];
    int E = in_sizes[1] / 2;
    const int* srcA = ei;
    const int* dstA = ei + E;
    int NB = (n + BW - 1) >> BSHIFT;      // 391 for n=200000 (requires NB < 512)

    size_t o = 0;
    auto carve = [&](size_t bytes) {
        void* p = (char*)d_ws + o;
        o = (o + bytes + 255) & ~(size_t)255;
        return p;
    };
    int* bucketCount  = (int*)carve(BW * 4);
    int* bucketBase   = (int*)carve((BW + 1) * 4);
    int* bucketCursor = (int*)carve(BW * 4);
    int* csrOff       = (int*)carve((size_t)n * 4);
    int* deg          = (int*)carve((size_t)n * 4);
    float* dinv       = (float*)carve((size_t)n * 4);
    float* xd         = (float*)carve((size_t)n * 4);
    unsigned int* spk = (unsigned int*)carve((size_t)n * 4);
    unsigned int* binned = (unsigned int*)carve((size_t)E * 4);
    int* csrSrc       = (int*)carve((size_t)E * 4);
    (void)ws_size;

    hipMemsetAsync(bucketCount, 0, BW * 4, stream);

    k_bhist<<<512, BLK, 0, stream>>>(dstA, bucketCount, E);
    k_bscan<<<1, BLK, 0, stream>>>(bucketCount, bucketBase, bucketCursor, NB, E);
    k_bin<<<(E + CHUNK - 1) / CHUNK, BLK, 0, stream>>>(srcA, dstA, bucketCursor, binned, E);
    k_csr<<<NB, BLK, 0, stream>>>(binned, bucketBase, x, csrOff, deg, dinv, xd, csrSrc, n);

    int nodeBlocks1 = (n + (BLKL / 4) - 1) / (BLKL / 4);
    k_l1<<<nodeBlocks1, BLKL, 0, stream>>>(csrOff, deg, csrSrc, xd, dinv, spk, n);
    int nodeBlocks2 = (n + (BLKL / 2) - 1) / (BLKL / 2);
    k_l2<<<nodeBlocks2, BLKL, 0, stream>>>(csrOff, deg, csrSrc, spk, dinv,
                                           W1, b1, W2, b2, Wl, bl, out, n);
}

// Round 14
// 134.085 us; speedup vs baseline: 1.1776x; 1.1776x over previous
//
#include <hip/hip_runtime.h>

#define BSHIFT 9
#define BW 512            // nodes per bucket == bins
#define BLK 512
#define BLKL 256          // block size for layer kernels
#define CHUNK 8192        // edges per k_bin block (16/thread)
#define BCAP 20480        // fixed per-bucket capacity in binned/csrSrc (mean 16384, +32 sigma)
#define CSR_CAP 18432     // LDS staging capacity (expected bucket ~16.4K edges)

// ---- block-wide exclusive scan over BLK=512 ints (wave shfl + 8-entry LDS) ----
__device__ __forceinline__ int blockScanExcl512(int v, int tid, int* wsum) {
    int lane = tid & 63;
    int w = tid >> 6;                       // 8 waves
    int incl = v;
#pragma unroll
    for (int d = 1; d < 64; d <<= 1) {
        int u = __shfl_up(incl, d, 64);
        if (lane >= d) incl += u;
    }
    if (lane == 63) wsum[w] = incl;
    __syncthreads();
    if (tid < 64) {
        int x = (tid < 8) ? wsum[tid] : 0;
#pragma unroll
        for (int d = 1; d < 8; d <<= 1) {
            int u = __shfl_up(x, d, 64);
            if (lane >= d) x += u;
        }
        if (tid < 8) wsum[tid] = x;         // inclusive scan of wave totals
    }
    __syncthreads();
    int base = (w == 0) ? 0 : wsum[w - 1];
    return base + incl - v;
}

// ---------------- pass 1: chunk counting-sort by dst-bucket, coalesced flush ----------------
// Fixed-capacity bucket slots: no histogram/scan pre-pass needed.
__global__ __launch_bounds__(BLK) void k_bin(const int* __restrict__ src,
                                             const int* __restrict__ dst,
                                             int* __restrict__ cnt,
                                             unsigned int* __restrict__ binned, int E) {
    __shared__ int h0[BW], h1[BW];
    __shared__ int excl[BW], cur[BW], gbase[BW];
    __shared__ unsigned int vals[CHUNK];      // 32 KB
    __shared__ unsigned short bkt[CHUNK];     // 16 KB
    __shared__ int wsum[8];
    int t = threadIdx.x;
    int base = blockIdx.x * CHUNK;
    int cnt_e = min(CHUNK, E - base);
    h0[t] = 0; h1[t] = 0;
    __syncthreads();
    int* hr = ((t >> 6) & 1) ? h1 : h0;

    int d16[16], s16[16];
    int myBase = base + t * 16;
    int nb = 0;
    if (myBase + 16 <= E) {
        const int4* dp = (const int4*)(dst + myBase);
        const int4* sp = (const int4*)(src + myBase);
#pragma unroll
        for (int k = 0; k < 4; ++k) {
            int4 a = dp[k];
            d16[4 * k] = a.x; d16[4 * k + 1] = a.y; d16[4 * k + 2] = a.z; d16[4 * k + 3] = a.w;
            int4 c = sp[k];
            s16[4 * k] = c.x; s16[4 * k + 1] = c.y; s16[4 * k + 2] = c.z; s16[4 * k + 3] = c.w;
        }
        nb = 16;
    } else {
        for (int k = 0; k < 16; ++k) {
            int idx = myBase + k;
            if (idx < E) { d16[k] = dst[idx]; s16[k] = src[idx]; ++nb; }
        }
    }
    for (int k = 0; k < nb; ++k) atomicAdd(&hr[d16[k] >> BSHIFT], 1);
    __syncthreads();
    int hv = h0[t] + h1[t];
    int ex = blockScanExcl512(hv, t, wsum);
    excl[t] = ex;
    cur[t] = ex;
    if (hv) gbase[t] = t * BCAP + atomicAdd(&cnt[t], hv);
    __syncthreads();
    for (int k = 0; k < nb; ++k) {
        int b = d16[k] >> BSHIFT;
        int r = atomicAdd(&cur[b], 1);
        vals[r] = ((unsigned int)s16[k] << BSHIFT) | (unsigned int)(d16[k] & (BW - 1));
        bkt[r] = (unsigned short)b;
    }
    __syncthreads();
    for (int i = t; i < cnt_e; i += BLK) {
        int b = bkt[i];
        binned[gbase[b] + (i - excl[b])] = vals[i];
    }
}

// ---------------- pass 2: per-bucket per-node counting sort -> CSR (+deg/dinv/xd) ----------------
// LDS-staged output: scatter hits LDS, flush is a contiguous streaming write.
__global__ __launch_bounds__(BLK) void k_csr(const unsigned int* __restrict__ binned,
                                             const int* __restrict__ cnt,
                                             const float* __restrict__ x,
                                             int* __restrict__ csrOff,
                                             int* __restrict__ deg,
                                             float* __restrict__ dinv,
                                             float* __restrict__ xd,
                                             int* __restrict__ csrSrc, int n) {
    __shared__ int dh0[BW], dh1[BW];
    __shared__ int cursor[BW];
    __shared__ int wsum[8];
    __shared__ int stage[CSR_CAP];         // 72 KB
    int t = threadIdx.x;
    int b = blockIdx.x;
    int ebase = b * BCAP;
    int ecnt = cnt[b];
    dh0[t] = 0; dh1[t] = 0;
    __syncthreads();
    int* dh = ((t >> 6) & 1) ? dh1 : dh0;
    for (int i = t; i < ecnt; i += BLK)
        atomicAdd(&dh[binned[ebase + i] & (BW - 1)], 1);
    __syncthreads();
    int c = dh0[t] + dh1[t];
    int ex = blockScanExcl512(c, t, wsum);
    cursor[t] = ex;
    int nodeBase = b << BSHIFT;
    if (t < min(BW, n - nodeBase)) {
        int node = nodeBase + t;
        csrOff[node] = ebase + ex;
        deg[node] = c;
        float r = rsqrtf((float)(c + 1));
        dinv[node] = r;
        xd[node] = x[node] * r;
    }
    __syncthreads();
    for (int i = t; i < ecnt; i += BLK) {
        unsigned int v = binned[ebase + i];
        int r = atomicAdd(&cursor[v & (BW - 1)], 1);
        int sv = (int)(v >> BSHIFT);
        if (r < CSR_CAP) stage[r] = sv;
        else csrSrc[ebase + r] = sv;
    }
    __syncthreads();
    int m = min(ecnt, CSR_CAP);
    for (int i = t; i < m; i += BLK)
        csrSrc[ebase + i] = stage[i];
}

// ---------------- pass 3: layer-1 scalar aggregate -> spk[n] = pack(s_i, deg8) ----------------
// 4 lanes per node; s packed into high 24 bits (round-to-nearest), deg8 in low 8.
__global__ __launch_bounds__(BLKL) void k_l1(const int* __restrict__ csrOff,
                                             const int* __restrict__ deg,
                                             const int* __restrict__ csrSrc,
                                             const float* __restrict__ xd,
                                             const float* __restrict__ dinv,
                                             unsigned int* __restrict__ spk, int n) {
    int tid = threadIdx.x;
    int q = tid & 3;
    int node = blockIdx.x * (BLKL / 4) + (tid >> 2);
    if (node >= n) return;
    int start = csrOff[node];
    int dc = deg[node];
    float u = 0.f;
    int e = q;
    for (; e + 4 < dc; e += 8) {
        int s0 = csrSrc[start + e];
        int s1 = csrSrc[start + e + 4];
        u += xd[s0] + xd[s1];
    }
    for (; e < dc; e += 4)
        u += xd[csrSrc[start + e]];
    u += __shfl_xor(u, 1, 64);
    u += __shfl_xor(u, 2, 64);
    if (q == 0) {
        float di = dinv[node];
        float s = di * (u + xd[node]);
        unsigned int us = (__float_as_uint(s) + 0x80u) & 0xFFFFFF00u;  // round to 24-bit
        unsigned int d8 = (unsigned int)min(dc, 255);
        spk[node] = us | d8;
    }
}

// ---------------- pass 4: layer-2, 4 lanes per node, packed 4B gather ----------------
// G_j = sum_src relu(W1[j]*s_src+b1[j])*di_src (+self);  A[k]=sum_j W2[j][k]*G_j
// out[i] = relu(dinv_i*A + b2) . Wl + bl
__global__ __launch_bounds__(BLKL) void k_l2(const int* __restrict__ csrOff,
                                             const int* __restrict__ deg,
                                             const int* __restrict__ csrSrc,
                                             const unsigned int* __restrict__ spk,
                                             const float* __restrict__ dinv,
                                             const float* __restrict__ W1,
                                             const float* __restrict__ b1,
                                             const float* __restrict__ W2,
                                             const float* __restrict__ b2,
                                             const float* __restrict__ Wl,
                                             const float* __restrict__ bl,
                                             float* __restrict__ out, int n) {
    __shared__ float sW2[256];
    __shared__ float di_tab[256];
    int tid = threadIdx.x;
    sW2[tid] = W2[tid];
    di_tab[tid] = rsqrtf((float)(tid + 1));   // exact di for deg 0..254
    int q = tid & 3;
    int node = blockIdx.x * (BLKL / 4) + (tid >> 2);

    // per-lane W1 (SGPR ok) and b1 (pin to VGPR so unrolled fma avoids per-use v_mov)
    float w1r[16], b1r[16];
#pragma unroll
    for (int j = 0; j < 16; ++j) {
        w1r[j] = W1[j];
        float bv = b1[j];
        asm volatile("" : "+v"(bv));
        b1r[j] = bv;
    }
    float4 b2q = *(const float4*)(b2 + 4 * q);
    float4 wlq = *(const float4*)(Wl + 4 * q);
    float blv = bl[0];
    __syncthreads();
    if (node >= n) return;

    int start = csrOff[node];
    int dc = deg[node];
    float G[16];
#pragma unroll
    for (int j = 0; j < 16; ++j) G[j] = 0.f;

    unsigned int uself = spk[node];
    float dself = dinv[node];
    if (q == 0) {
        float sself = __uint_as_float(uself & 0xFFFFFF00u);
#pragma unroll
        for (int j = 0; j < 16; ++j)
            G[j] = fmaf(fmaxf(fmaf(w1r[j], sself, b1r[j]), 0.f), dself, G[j]);
    }

#define EDGEACC(u, srcidx)                                                \
    {                                                                     \
        float s_ = __uint_as_float((u) & 0xFFFFFF00u);                    \
        unsigned int d8_ = (u) & 255u;                                    \
        float di_ = di_tab[d8_];                                          \
        if (__builtin_expect(d8_ == 255u, 0)) di_ = dinv[srcidx];         \
        _Pragma("unroll")                                                 \
        for (int j = 0; j < 16; ++j)                                      \
            G[j] = fmaf(fmaxf(fmaf(w1r[j], s_, b1r[j]), 0.f), di_, G[j]); \
    }

    int e = q;
    for (; e + 12 < dc; e += 16) {
        int s0 = csrSrc[start + e];
        int s1 = csrSrc[start + e + 4];
        int s2 = csrSrc[start + e + 8];
        int s3 = csrSrc[start + e + 12];
        unsigned int u0 = spk[s0];
        unsigned int u1 = spk[s1];
        unsigned int u2 = spk[s2];
        unsigned int u3 = spk[s3];
        EDGEACC(u0, s0) EDGEACC(u1, s1) EDGEACC(u2, s2) EDGEACC(u3, s3)
    }
    for (; e < dc; e += 4) {
        int s0 = csrSrc[start + e];
        unsigned int u0 = spk[s0];
        EDGEACC(u0, s0)
    }
#undef EDGEACC

    // 2-step butterfly: all 4 lanes of the quad end with the full G[16]
#pragma unroll
    for (int j = 0; j < 16; ++j) {
        G[j] += __shfl_xor(G[j], 1, 64);
        G[j] += __shfl_xor(G[j], 2, 64);
    }

    // W2 matvec: lane q owns output channels 4q..4q+3 (broadcast LDS reads)
    float4 A = make_float4(0.f, 0.f, 0.f, 0.f);
#pragma unroll
    for (int j = 0; j < 16; ++j) {
        float4 w = *(const float4*)(&sW2[j * 16 + 4 * q]);
        A.x = fmaf(w.x, G[j], A.x);
        A.y = fmaf(w.y, G[j], A.y);
        A.z = fmaf(w.z, G[j], A.z);
        A.w = fmaf(w.w, G[j], A.w);
    }

    float v0 = fmaxf(fmaf(dself, A.x, b2q.x), 0.f);
    float v1 = fmaxf(fmaf(dself, A.y, b2q.y), 0.f);
    float v2 = fmaxf(fmaf(dself, A.z, b2q.z), 0.f);
    float v3 = fmaxf(fmaf(dself, A.w, b2q.w), 0.f);
    float p = fmaf(v0, wlq.x, fmaf(v1, wlq.y, fmaf(v2, wlq.z, v3 * wlq.w)));
    p += __shfl_xor(p, 1, 64);
    p += __shfl_xor(p, 2, 64);
    if (q == 0) out[node] = p + blv;
}

extern "C" void kernel_launch(void* const* d_in, const int* in_sizes, int n_in,
                              void* d_out, int out_size, void* d_ws, size_t ws_size,
                              hipStream_t stream) {
    const float* x  = (const float*)d_in[0];
    const int*   ei = (const int*)d_in[1];
    const float* W1 = (const float*)d_in[2];
    const float* b1 = (const float*)d_in[3];
    const float* W2 = (const float*)d_in[4];
    const float* b2 = (const float*)d_in[5];
    const float* Wl = (const float*)d_in[6];
    const float* bl = (const float*)d_in[7];
    float* out = (float*)d_out;

    int n = in_sizes[0];
    int E = in_sizes[1] / 2;
    const int* srcA = ei;
    const int* dstA = ei + E;
    int NB = (n + BW - 1) >> BSHIFT;      // 391 for n=200000 (requires NB <= 512)

    size_t o = 0;
    auto carve = [&](size_t bytes) {
        void* p = (char*)d_ws + o;
        o = (o + bytes + 255) & ~(size_t)255;
        return p;
    };
    int* cnt          = (int*)carve(BW * 4);
    int* csrOff       = (int*)carve((size_t)n * 4);
    int* deg          = (int*)carve((size_t)n * 4);
    float* dinv       = (float*)carve((size_t)n * 4);
    float* xd         = (float*)carve((size_t)n * 4);
    unsigned int* spk = (unsigned int*)carve((size_t)n * 4);
    unsigned int* binned = (unsigned int*)carve((size_t)NB * BCAP * 4);
    int* csrSrc       = (int*)carve((size_t)NB * BCAP * 4);
    (void)ws_size;

    hipMemsetAsync(cnt, 0, BW * 4, stream);

    k_bin<<<(E + CHUNK - 1) / CHUNK, BLK, 0, stream>>>(srcA, dstA, cnt, binned, E);
    k_csr<<<NB, BLK, 0, stream>>>(binned, cnt, x, csrOff, deg, dinv, xd, csrSrc, n);

    int nodeBlocks = (n + (BLKL / 4) - 1) / (BLKL / 4);
    k_l1<<<nodeBlocks, BLKL, 0, stream>>>(csrOff, deg, csrSrc, xd, dinv, spk, n);
    k_l2<<<nodeBlocks, BLKL, 0, stream>>>(csrOff, deg, csrSrc, spk, dinv,
                                          W1, b1, W2, b2, Wl, bl, out, n);
}

// Round 15
// 132.503 us; speedup vs baseline: 1.1916x; 1.0119x over previous
//
#include <hip/hip_runtime.h>

#define BSHIFT 9
#define BW 512            // nodes per bucket == bins
#define BLK 512
#define BLKL 256          // block size for layer kernels
#define CHUNK 8192        // edges per k_bin block (16/thread)
#define BCAP 20480        // fixed per-bucket capacity in binned/csrSrc (mean 16384, +32 sigma)
#define CSR_CAP 18432     // LDS staging capacity (expected bucket ~16.4K edges)

// ---- block-wide exclusive scan over BLK=512 ints (wave shfl + 8-entry LDS) ----
__device__ __forceinline__ int blockScanExcl512(int v, int tid, int* wsum) {
    int lane = tid & 63;
    int w = tid >> 6;                       // 8 waves
    int incl = v;
#pragma unroll
    for (int d = 1; d < 64; d <<= 1) {
        int u = __shfl_up(incl, d, 64);
        if (lane >= d) incl += u;
    }
    if (lane == 63) wsum[w] = incl;
    __syncthreads();
    if (tid < 64) {
        int x = (tid < 8) ? wsum[tid] : 0;
#pragma unroll
        for (int d = 1; d < 8; d <<= 1) {
            int u = __shfl_up(x, d, 64);
            if (lane >= d) x += u;
        }
        if (tid < 8) wsum[tid] = x;         // inclusive scan of wave totals
    }
    __syncthreads();
    int base = (w == 0) ? 0 : wsum[w - 1];
    return base + incl - v;
}

// ---------------- pass 0: zero the bucket cursors (replaces pathological runtime fill) ----------------
__global__ __launch_bounds__(BW) void k_zero(int* __restrict__ cnt) {
    cnt[threadIdx.x] = 0;
}

// ---------------- pass 1: chunk counting-sort by dst-bucket, coalesced flush ----------------
// Fixed-capacity bucket slots: no histogram/scan pre-pass needed.
__global__ __launch_bounds__(BLK) void k_bin(const int* __restrict__ src,
                                             const int* __restrict__ dst,
                                             int* __restrict__ cnt,
                                             unsigned int* __restrict__ binned, int E) {
    __shared__ int h0[BW], h1[BW];
    __shared__ int excl[BW], cur[BW], gbase[BW];
    __shared__ unsigned int vals[CHUNK];      // 32 KB
    __shared__ unsigned short bkt[CHUNK];     // 16 KB
    __shared__ int wsum[8];
    int t = threadIdx.x;
    int base = blockIdx.x * CHUNK;
    int cnt_e = min(CHUNK, E - base);
    h0[t] = 0; h1[t] = 0;
    __syncthreads();
    int* hr = ((t >> 6) & 1) ? h1 : h0;

    int d16[16], s16[16];
    int myBase = base + t * 16;
    int nb = 0;
    if (myBase + 16 <= E) {
        const int4* dp = (const int4*)(dst + myBase);
        const int4* sp = (const int4*)(src + myBase);
#pragma unroll
        for (int k = 0; k < 4; ++k) {
            int4 a = dp[k];
            d16[4 * k] = a.x; d16[4 * k + 1] = a.y; d16[4 * k + 2] = a.z; d16[4 * k + 3] = a.w;
            int4 c = sp[k];
            s16[4 * k] = c.x; s16[4 * k + 1] = c.y; s16[4 * k + 2] = c.z; s16[4 * k + 3] = c.w;
        }
        nb = 16;
    } else {
        for (int k = 0; k < 16; ++k) {
            int idx = myBase + k;
            if (idx < E) { d16[k] = dst[idx]; s16[k] = src[idx]; ++nb; }
        }
    }
    for (int k = 0; k < nb; ++k) atomicAdd(&hr[d16[k] >> BSHIFT], 1);
    __syncthreads();
    int hv = h0[t] + h1[t];
    int ex = blockScanExcl512(hv, t, wsum);
    excl[t] = ex;
    cur[t] = ex;
    if (hv) gbase[t] = t * BCAP + atomicAdd(&cnt[t], hv);
    __syncthreads();
    for (int k = 0; k < nb; ++k) {
        int b = d16[k] >> BSHIFT;
        int r = atomicAdd(&cur[b], 1);
        vals[r] = ((unsigned int)s16[k] << BSHIFT) | (unsigned int)(d16[k] & (BW - 1));
        bkt[r] = (unsigned short)b;
    }
    __syncthreads();
    for (int i = t; i < cnt_e; i += BLK) {
        int b = bkt[i];
        binned[gbase[b] + (i - excl[b])] = vals[i];
    }
}

// ---------------- pass 2: per-bucket per-node counting sort -> CSR (+deg/dinv/xd) ----------------
// LDS-staged output: scatter hits LDS, flush is a contiguous streaming write.
__global__ __launch_bounds__(BLK) void k_csr(const unsigned int* __restrict__ binned,
                                             const int* __restrict__ cnt,
                                             const float* __restrict__ x,
                                             int* __restrict__ csrOff,
                                             int* __restrict__ deg,
                                             float* __restrict__ dinv,
                                             float* __restrict__ xd,
                                             int* __restrict__ csrSrc, int n) {
    __shared__ int dh0[BW], dh1[BW];
    __shared__ int cursor[BW];
    __shared__ int wsum[8];
    __shared__ int stage[CSR_CAP];         // 72 KB
    int t = threadIdx.x;
    int b = blockIdx.x;
    int ebase = b * BCAP;
    int ecnt = cnt[b];
    dh0[t] = 0; dh1[t] = 0;
    __syncthreads();
    int* dh = ((t >> 6) & 1) ? dh1 : dh0;
    for (int i = t; i < ecnt; i += BLK)
        atomicAdd(&dh[binned[ebase + i] & (BW - 1)], 1);
    __syncthreads();
    int c = dh0[t] + dh1[t];
    int ex = blockScanExcl512(c, t, wsum);
    cursor[t] = ex;
    int nodeBase = b << BSHIFT;
    if (t < min(BW, n - nodeBase)) {
        int node = nodeBase + t;
        csrOff[node] = ebase + ex;
        deg[node] = c;
        float r = rsqrtf((float)(c + 1));
        dinv[node] = r;
        xd[node] = x[node] * r;
    }
    __syncthreads();
    for (int i = t; i < ecnt; i += BLK) {
        unsigned int v = binned[ebase + i];
        int r = atomicAdd(&cursor[v & (BW - 1)], 1);
        int sv = (int)(v >> BSHIFT);
        if (r < CSR_CAP) stage[r] = sv;
        else csrSrc[ebase + r] = sv;
    }
    __syncthreads();
    int m = min(ecnt, CSR_CAP);
    for (int i = t; i < m; i += BLK)
        csrSrc[ebase + i] = stage[i];
}

// ---------------- pass 3: layer-1 scalar aggregate -> spk[n] = pack(s_i, deg8) ----------------
// 4 lanes per node; s packed into high 24 bits (round-to-nearest), deg8 in low 8.
__global__ __launch_bounds__(BLKL) void k_l1(const int* __restrict__ csrOff,
                                             const int* __restrict__ deg,
                                             const int* __restrict__ csrSrc,
                                             const float* __restrict__ xd,
                                             const float* __restrict__ dinv,
                                             unsigned int* __restrict__ spk, int n) {
    int tid = threadIdx.x;
    int q = tid & 3;
    int node = blockIdx.x * (BLKL / 4) + (tid >> 2);
    if (node >= n) return;
    int start = csrOff[node];
    int dc = deg[node];
    float u = 0.f;
    int e = q;
    for (; e + 4 < dc; e += 8) {
        int s0 = csrSrc[start + e];
        int s1 = csrSrc[start + e + 4];
        u += xd[s0] + xd[s1];
    }
    for (; e < dc; e += 4)
        u += xd[csrSrc[start + e]];
    u += __shfl_xor(u, 1, 64);
    u += __shfl_xor(u, 2, 64);
    if (q == 0) {
        float di = dinv[node];
        float s = di * (u + xd[node]);
        unsigned int us = (__float_as_uint(s) + 0x80u) & 0xFFFFFF00u;  // round to 24-bit
        unsigned int d8 = (unsigned int)min(dc, 255);
        spk[node] = us | d8;
    }
}

// ---------------- pass 4: layer-2, 4 lanes per node, packed 4B gather ----------------
// G_j = sum_src relu(W1[j]*s_src+b1[j])*di_src (+self);  A[k]=sum_j W2[j][k]*G_j
// out[i] = relu(dinv_i*A + b2) . Wl + bl
__global__ __launch_bounds__(BLKL) void k_l2(const int* __restrict__ csrOff,
                                             const int* __restrict__ deg,
                                             const int* __restrict__ csrSrc,
                                             const unsigned int* __restrict__ spk,
                                             const float* __restrict__ dinv,
                                             const float* __restrict__ W1,
                                             const float* __restrict__ b1,
                                             const float* __restrict__ W2,
                                             const float* __restrict__ b2,
                                             const float* __restrict__ Wl,
                                             const float* __restrict__ bl,
                                             float* __restrict__ out, int n) {
    __shared__ float sW2[256];
    __shared__ float di_tab[256];
    int tid = threadIdx.x;
    sW2[tid] = W2[tid];
    di_tab[tid] = rsqrtf((float)(tid + 1));   // exact di for deg 0..254
    int q = tid & 3;
    int node = blockIdx.x * (BLKL / 4) + (tid >> 2);

    // per-lane W1 (SGPR ok) and b1 (pin to VGPR so unrolled fma avoids per-use v_mov)
    float w1r[16], b1r[16];
#pragma unroll
    for (int j = 0; j < 16; ++j) {
        w1r[j] = W1[j];
        float bv = b1[j];
        asm volatile("" : "+v"(bv));
        b1r[j] = bv;
    }
    float4 b2q = *(const float4*)(b2 + 4 * q);
    float4 wlq = *(const float4*)(Wl + 4 * q);
    float blv = bl[0];
    __syncthreads();
    if (node >= n) return;

    int start = csrOff[node];
    int dc = deg[node];
    float G[16];
#pragma unroll
    for (int j = 0; j < 16; ++j) G[j] = 0.f;

    unsigned int uself = spk[node];
    float dself = dinv[node];
    if (q == 0) {
        float sself = __uint_as_float(uself & 0xFFFFFF00u);
#pragma unroll
        for (int j = 0; j < 16; ++j)
            G[j] = fmaf(fmaxf(fmaf(w1r[j], sself, b1r[j]), 0.f), dself, G[j]);
    }

#define EDGEACC(u, srcidx)                                                \
    {                                                                     \
        float s_ = __uint_as_float((u) & 0xFFFFFF00u);                    \
        unsigned int d8_ = (u) & 255u;                                    \
        float di_ = di_tab[d8_];                                          \
        if (__builtin_expect(d8_ == 255u, 0)) di_ = dinv[srcidx];         \
        _Pragma("unroll")                                                 \
        for (int j = 0; j < 16; ++j)                                      \
            G[j] = fmaf(fmaxf(fmaf(w1r[j], s_, b1r[j]), 0.f), di_, G[j]); \
    }

    int e = q;
    for (; e + 12 < dc; e += 16) {
        int s0 = csrSrc[start + e];
        int s1 = csrSrc[start + e + 4];
        int s2 = csrSrc[start + e + 8];
        int s3 = csrSrc[start + e + 12];
        unsigned int u0 = spk[s0];
        unsigned int u1 = spk[s1];
        unsigned int u2 = spk[s2];
        unsigned int u3 = spk[s3];
        EDGEACC(u0, s0) EDGEACC(u1, s1) EDGEACC(u2, s2) EDGEACC(u3, s3)
    }
    for (; e < dc; e += 4) {
        int s0 = csrSrc[start + e];
        unsigned int u0 = spk[s0];
        EDGEACC(u0, s0)
    }
#undef EDGEACC

    // 2-step butterfly: all 4 lanes of the quad end with the full G[16]
#pragma unroll
    for (int j = 0; j < 16; ++j) {
        G[j] += __shfl_xor(G[j], 1, 64);
        G[j] += __shfl_xor(G[j], 2, 64);
    }

    // W2 matvec: lane q owns output channels 4q..4q+3 (broadcast LDS reads)
    float4 A = make_float4(0.f, 0.f, 0.f, 0.f);
#pragma unroll
    for (int j = 0; j < 16; ++j) {
        float4 w = *(const float4*)(&sW2[j * 16 + 4 * q]);
        A.x = fmaf(w.x, G[j], A.x);
        A.y = fmaf(w.y, G[j], A.y);
        A.z = fmaf(w.z, G[j], A.z);
        A.w = fmaf(w.w, G[j], A.w);
    }

    float v0 = fmaxf(fmaf(dself, A.x, b2q.x), 0.f);
    float v1 = fmaxf(fmaf(dself, A.y, b2q.y), 0.f);
    float v2 = fmaxf(fmaf(dself, A.z, b2q.z), 0.f);
    float v3 = fmaxf(fmaf(dself, A.w, b2q.w), 0.f);
    float p = fmaf(v0, wlq.x, fmaf(v1, wlq.y, fmaf(v2, wlq.z, v3 * wlq.w)));
    p += __shfl_xor(p, 1, 64);
    p += __shfl_xor(p, 2, 64);
    if (q == 0) out[node] = p + blv;
}

extern "C" void kernel_launch(void* const* d_in, const int* in_sizes, int n_in,
                              void* d_out, int out_size, void* d_ws, size_t ws_size,
                              hipStream_t stream) {
    const float* x  = (const float*)d_in[0];
    const int*   ei = (const int*)d_in[1];
    const float* W1 = (const float*)d_in[2];
    const float* b1 = (const float*)d_in[3];
    const float* W2 = (const float*)d_in[4];
    const float* b2 = (const float*)d_in[5];
    const float* Wl = (const float*)d_in[6];
    const float* bl = (const float*)d_in[7];
    float* out = (float*)d_out;

    int n = in_sizes[0];
    int E = in_sizes[1] / 2;
    const int* srcA = ei;
    const int* dstA = ei + E;
    int NB = (n + BW - 1) >> BSHIFT;      // 391 for n=200000 (requires NB <= 512)

    size_t o = 0;
    auto carve = [&](size_t bytes) {
        void* p = (char*)d_ws + o;
        o = (o + bytes + 255) & ~(size_t)255;
        return p;
    };
    int* cnt          = (int*)carve(BW * 4);
    int* csrOff       = (int*)carve((size_t)n * 4);
    int* deg          = (int*)carve((size_t)n * 4);
    float* dinv       = (float*)carve((size_t)n * 4);
    float* xd         = (float*)carve((size_t)n * 4);
    unsigned int* spk = (unsigned int*)carve((size_t)n * 4);
    unsigned int* binned = (unsigned int*)carve((size_t)NB * BCAP * 4);
    int* csrSrc       = (int*)carve((size_t)NB * BCAP * 4);
    (void)ws_size;

    k_zero<<<1, BW, 0, stream>>>(cnt);
    k_bin<<<(E + CHUNK - 1) / CHUNK, BLK, 0, stream>>>(srcA, dstA, cnt, binned, E);
    k_csr<<<NB, BLK, 0, stream>>>(binned, cnt, x, csrOff, deg, dinv, xd, csrSrc, n);

    int nodeBlocks = (n + (BLKL / 4) - 1) / (BLKL / 4);
    k_l1<<<nodeBlocks, BLKL, 0, stream>>>(csrOff, deg, csrSrc, xd, dinv, spk, n);
    k_l2<<<nodeBlocks, BLKL, 0, stream>>>(csrOff, deg, csrSrc, spk, dinv,
                                          W1, b1, W2, b2, Wl, bl, out, n);
}